// Round 1
// baseline (356.225 us; speedup 1.0000x reference)
//
#include <hip/hip_runtime.h>

using f4 = __attribute__((ext_vector_type(4))) float;

// Output layout (floats): se [4,64,8,8,64,64] | rel_out [4,64,8] | ant [4,128,8,8]
#define REL_OFF 67108864ull
#define ANT_OFF 67110912ull

// Workspace layout (floats)
#define WS_PT 0       // 4096  : Pt[d][e] = piece_emb[e][d]
#define WS_A1 4096    // 32    : a1[f]
#define WS_BT 4128    // 2048  : bt[f][hw]
#define WS_CT 6176    // 2048  : ct[f][hw]
#define WS_Y1 8224    // 32768 : relu(conv1(x))  [4,128,8,8]

__global__ __launch_bounds__(1024) void precompute_kernel(
    const float* __restrict__ P,   // piece_emb [64e][64d]
    const float* __restrict__ Q,   // pos_emb   [64hw][64d]
    const float* __restrict__ w1,  // [32f][64e]
    const float* __restrict__ b1,  // [32]
    float* __restrict__ ws) {
  __shared__ float Plds[4096];   // [e][d]
  __shared__ float Ptl[4096];    // [d][e]
  __shared__ float Qlds[4096];   // [hw][d]
  __shared__ float W1P[2048];    // [f][d]
  __shared__ float A[64], Cc[64], s1[32];
  int t = threadIdx.x;
  for (int i = t; i < 4096; i += 1024) { Plds[i] = P[i]; Qlds[i] = Q[i]; }
  __syncthreads();
  for (int i = t; i < 4096; i += 1024) {
    int d = i >> 6, e = i & 63;
    Ptl[i] = Plds[(e << 6) + d];
  }
  if (t < 64) {
    float s = 0.f;
    for (int d = 0; d < 64; ++d) { float p = Plds[(t << 6) + d]; s = fmaf(p, p, s); }
    A[t] = s;
  } else if (t < 128) {
    int hw = t - 64; float s = 0.f;
    for (int d = 0; d < 64; ++d) { float q = Qlds[(hw << 6) + d]; s = fmaf(q, q, s); }
    Cc[hw] = s;
  } else if (t < 160) {
    int f = t - 128; float s = 0.f;
    for (int e = 0; e < 64; ++e) s += w1[(f << 6) + e];
    s1[f] = s;
  }
  __syncthreads();
  for (int i = t; i < 4096; i += 1024) ws[WS_PT + i] = Ptl[i];
  if (t < 32) {
    float s = 0.f;
    for (int e = 0; e < 64; ++e) s = fmaf(A[e], w1[(t << 6) + e], s);
    ws[WS_A1 + t] = s;
  }
  for (int i = t; i < 2048; i += 1024) {
    int f = i >> 6, d = i & 63;
    float s = 0.f;
    for (int e = 0; e < 64; ++e) s = fmaf(w1[(f << 6) + e], Ptl[(d << 6) + e], s);
    W1P[i] = s;
  }
  __syncthreads();
  for (int i = t; i < 2048; i += 1024) {
    int f = i >> 6, hw = i & 63;
    float s = 0.f;
    for (int d = 0; d < 64; ++d) s = fmaf(W1P[(f << 6) + d], Qlds[(hw << 6) + d], s);
    ws[WS_BT + i] = s;
    ws[WS_CT + i] = fmaf(Cc[hw], s1[f], b1[f]);
  }
}

// One block per (b,c,hw); writes the 64x64 (d,e) tile = 16 KiB, coalesced f4.
__global__ __launch_bounds__(256) void se_kernel(
    const float* __restrict__ x,   // [4][65][64]
    const float* __restrict__ pt,  // [d][e]
    const float* __restrict__ q,   // pos_emb [hw][d]
    float* __restrict__ out) {
  int blk = blockIdx.x;            // ((b*64+c)*64+hw)
  int hw = blk & 63, bc = blk >> 6;
  int b = bc >> 6, c = bc & 63;
  float xv = x[((b * 65 + c) << 6) + hw];
  int t = threadIdx.x;
  const f4* pt4 = (const f4*)pt;
  f4* out4 = (f4*)(out + ((size_t)blk << 12));
#pragma unroll
  for (int k = 0; k < 4; ++k) {
    int i4 = t + (k << 8);
    int d = i4 >> 4;
    float qd = q[(hw << 6) + d];
    f4 p = pt4[i4];
    f4 r;
    r[0] = fmaf(xv, p[0], qd);
    r[1] = fmaf(xv, p[1], qd);
    r[2] = fmaf(xv, p[2], qd);
    r[3] = fmaf(xv, p[3], qd);
    __builtin_nontemporal_store(r, out4 + i4);
  }
}

// Closed-form rel_out: one block per (b,c).
__global__ __launch_bounds__(256) void rel_kernel(
    const float* __restrict__ x,   // [4][65][64]
    const float* __restrict__ bt,  // [f][hw]
    const float* __restrict__ ct,  // [f][hw]
    const float* __restrict__ a1,  // [32]
    const float* __restrict__ w2,  // [32]
    const float* __restrict__ b2,  // [1]
    float* __restrict__ out) {     // [4*64][8]
  __shared__ float xl[4096];       // [s][hw]
  __shared__ float a1l[32], w2l[32];
  __shared__ float red[8];
  int t = threadIdx.x;
  int bc = blockIdx.x; int b = bc >> 6, c = bc & 63;
  for (int i = t; i < 4096; i += 256) {
    int s = i >> 6, hw = i & 63;
    xl[i] = x[((b * 65 + s) << 6) + hw];
  }
  if (t < 32) { a1l[t] = a1[t]; w2l[t] = w2[t]; }
  if (t < 8) red[t] = 0.f;
  int hw = t & 63, sg = t >> 6;
  float btr[32], ctr[32];
#pragma unroll
  for (int f = 0; f < 32; ++f) { btr[f] = bt[(f << 6) + hw]; ctr[f] = ct[(f << 6) + hw]; }
  __syncthreads();
  float b2v = b2[0];
  float xc = xl[(c << 6) + hw];
  float partial = 0.f;
  for (int s = sg; s < 64; s += 4) {
    float xs = xl[(s << 6) + hw];
    float u = xc * xs, v = xc + xs;
    float acc = b2v;
#pragma unroll
    for (int f = 0; f < 32; ++f) {
      float tt = fmaf(u, a1l[f], fmaf(v, btr[f], ctr[f]));
      acc = fmaf(fmaxf(tt, 0.f), w2l[f], acc);
    }
    partial += acc;
  }
  atomicAdd(&red[hw & 7], partial);
  __syncthreads();
  if (t < 8) out[bc * 8 + t] = red[t];
}

// conv1: 3x3 SAME, 65->128 ch, relu. Grid: 4b x 32 chunks (4 co each).
__global__ __launch_bounds__(256) void conv1_kernel(
    const float* __restrict__ x, const float* __restrict__ w,
    const float* __restrict__ bias, float* __restrict__ y1) {
  __shared__ float xp[6500];       // [65][10][10] zero-padded
  int blk = blockIdx.x;
  int b = blk >> 5, chunk = blk & 31;
  int t = threadIdx.x;
  for (int i = t; i < 6500; i += 256) xp[i] = 0.f;
  __syncthreads();
  for (int i = t; i < 4160; i += 256) {
    int ci = i >> 6, hw = i & 63;
    xp[ci * 100 + ((hw >> 3) + 1) * 10 + (hw & 7) + 1] = x[((b * 65 + ci) << 6) + hw];
  }
  __syncthreads();
  int hw = t & 63, wv = t >> 6;
  int h = hw >> 3, ww = hw & 7;
  int co = (chunk << 2) + wv;      // wave-uniform -> scalar weight loads
  float acc = bias[co];
  const float* wc = w + co * 585;
  for (int ci = 0; ci < 65; ++ci) {
    const float* xr = xp + ci * 100 + h * 10 + ww;
    const float* wr = wc + ci * 9;
#pragma unroll
    for (int dy = 0; dy < 3; ++dy)
#pragma unroll
      for (int dx = 0; dx < 3; ++dx)
        acc = fmaf(xr[dy * 10 + dx], wr[dy * 3 + dx], acc);
  }
  y1[(((b << 7) + co) << 6) + hw] = fmaxf(acc, 0.f);
}

// conv2: 3x3 SAME, 128->128 ch, no relu.
__global__ __launch_bounds__(256) void conv2_kernel(
    const float* __restrict__ y1, const float* __restrict__ w,
    const float* __restrict__ bias, float* __restrict__ out) {
  __shared__ float yp[12800];      // [128][10][10] zero-padded
  int blk = blockIdx.x;
  int b = blk >> 5, chunk = blk & 31;
  int t = threadIdx.x;
  for (int i = t; i < 12800; i += 256) yp[i] = 0.f;
  __syncthreads();
  for (int i = t; i < 8192; i += 256) {
    int ci = i >> 6, hw = i & 63;
    yp[ci * 100 + ((hw >> 3) + 1) * 10 + (hw & 7) + 1] = y1[(((b << 7) + ci) << 6) + hw];
  }
  __syncthreads();
  int hw = t & 63, wv = t >> 6;
  int h = hw >> 3, ww = hw & 7;
  int co = (chunk << 2) + wv;
  float acc = bias[co];
  const float* wc = w + co * 1152;
  for (int ci = 0; ci < 128; ++ci) {
    const float* xr = yp + ci * 100 + h * 10 + ww;
    const float* wr = wc + ci * 9;
#pragma unroll
    for (int dy = 0; dy < 3; ++dy)
#pragma unroll
      for (int dx = 0; dx < 3; ++dx)
        acc = fmaf(xr[dy * 10 + dx], wr[dy * 3 + dx], acc);
  }
  out[(((b << 7) + co) << 6) + hw] = acc;
}

extern "C" void kernel_launch(void* const* d_in, const int* in_sizes, int n_in,
                              void* d_out, int out_size, void* d_ws, size_t ws_size,
                              hipStream_t stream) {
  const float* x     = (const float*)d_in[0];
  const float* piece = (const float*)d_in[1];
  const float* pos   = (const float*)d_in[2];
  const float* w1    = (const float*)d_in[3];
  const float* b1    = (const float*)d_in[4];
  const float* w2    = (const float*)d_in[5];
  const float* b2    = (const float*)d_in[6];
  const float* c1w   = (const float*)d_in[7];
  const float* c1b   = (const float*)d_in[8];
  const float* c2w   = (const float*)d_in[9];
  const float* c2b   = (const float*)d_in[10];
  float* out = (float*)d_out;
  float* ws  = (float*)d_ws;

  precompute_kernel<<<1, 1024, 0, stream>>>(piece, pos, w1, b1, ws);
  se_kernel<<<16384, 256, 0, stream>>>(x, ws + WS_PT, pos, out);
  conv1_kernel<<<128, 256, 0, stream>>>(x, c1w, c1b, ws + WS_Y1);
  conv2_kernel<<<128, 256, 0, stream>>>(ws + WS_Y1, c2w, c2b, out + ANT_OFF);
  rel_kernel<<<256, 256, 0, stream>>>(x, ws + WS_BT, ws + WS_CT, ws + WS_A1, w2, b2, out + REL_OFF);
}

// Round 3
// 311.896 us; speedup vs baseline: 1.1421x; 1.1421x over previous
//
#include <hip/hip_runtime.h>

using f4 = __attribute__((ext_vector_type(4))) float;

// Output layout (floats): se [4,64,8,8,64,64] | rel_out [4,64,8] | ant [4,128,8,8]
#define REL_OFF 67108864ull
#define ANT_OFF 67110912ull

// Workspace layout (floats)
#define WS_A1 0      // 32    : a1[f]
#define WS_BT 32     // 2048  : bt[f][hw]
#define WS_CT 2080   // 2048  : ct[f][hw]
#define WS_Y1 4128   // 32768 : relu(conv1(x))  [4,128,8,8]

#define C1_BLOCKS 128
#define PRE_BLOCK 128
#define SE_BASE   129
#define SE_BLOCKS 4096   // one block per (b,c,hw/4): writes 64 KiB

// ---------------- K2: conv1 + precompute + se ----------------
__global__ __launch_bounds__(256) void k2_se_conv1_pre(
    const float* __restrict__ x,    // [4][65][64]
    const float* __restrict__ P,    // piece_emb [64e][64d]
    const float* __restrict__ Q,    // pos_emb   [64hw][64d]
    const float* __restrict__ w1,   // [32f][64e]
    const float* __restrict__ b1,   // [32]
    const float* __restrict__ c1w, const float* __restrict__ c1b,
    float* __restrict__ out, float* __restrict__ ws) {
  __shared__ float lds[6528];
  int bid = blockIdx.x, t = threadIdx.x;

  if (bid >= SE_BASE) {
    // ---- se role: block per (b,c,hwq); writes 4 consecutive 16 KiB (d,e) tiles
    int blk = bid - SE_BASE;
    int hwq = blk & 15, bc = blk >> 4;
    int b = bc >> 6, c = bc & 63;
    // stage P as lds[e*65 + d] (pad 65 -> 2-way conflicts only, free)
    for (int i = t; i < 4096; i += 256) lds[(i >> 6) * 65 + (i & 63)] = P[i];
    float xv[4];
    const float* xr = x + ((b * 65 + c) << 6) + (hwq << 2);
#pragma unroll
    for (int m = 0; m < 4; ++m) xv[m] = xr[m];
    __syncthreads();
    f4* outb = (f4*)out + ((size_t)bc << 16) + ((size_t)hwq << 12);
#pragma unroll
    for (int m = 0; m < 4; ++m) {
      int hw = (hwq << 2) + m;
#pragma unroll
      for (int k = 0; k < 4; ++k) {
        int i4 = t + (k << 8);
        int d = i4 >> 4, j = i4 & 15;
        float qd = Q[(hw << 6) + d];
        f4 r;
#pragma unroll
        for (int kk = 0; kk < 4; ++kk)
          r[kk] = fmaf(xv[m], lds[(((j << 2) + kk) * 65) + d], qd);
        __builtin_nontemporal_store(r, outb + (m << 10) + i4);
      }
    }
  } else if (bid < C1_BLOCKS) {
    // ---- conv1 role: 3x3 SAME, 65->128 ch, relu
    float* xp = lds;                 // [65][10][10] zero-padded
    int b = bid >> 5, chunk = bid & 31;
    for (int i = t; i < 6500; i += 256) xp[i] = 0.f;
    __syncthreads();
    for (int i = t; i < 4160; i += 256) {
      int ci = i >> 6, hw = i & 63;
      xp[ci * 100 + ((hw >> 3) + 1) * 10 + (hw & 7) + 1] = x[((b * 65 + ci) << 6) + hw];
    }
    __syncthreads();
    int hw = t & 63, wv = t >> 6;
    int h = hw >> 3, ww = hw & 7;
    int co = (chunk << 2) + wv;      // wave-uniform -> scalar weight loads
    float acc = c1b[co];
    const float* wc = c1w + co * 585;
    for (int ci = 0; ci < 65; ++ci) {
      const float* xr2 = xp + ci * 100 + h * 10 + ww;
      const float* wr = wc + ci * 9;
#pragma unroll
      for (int dy = 0; dy < 3; ++dy)
#pragma unroll
        for (int dx = 0; dx < 3; ++dx)
          acc = fmaf(xr2[dy * 10 + dx], wr[dy * 3 + dx], acc);
    }
    ws[WS_Y1 + (((b << 7) + co) << 6) + hw] = fmaxf(acc, 0.f);
  } else {
    // ---- precompute role (single block): a1, bt, ct for rel
    float* W1P = lds;          // [32f][64d]
    float* A   = lds + 2048;   // [64e]
    float* Cc  = lds + 2112;   // [64hw]
    float* s1  = lds + 2176;   // [32f]
    if (t < 64) {
      float s = 0.f;
      for (int d = 0; d < 64; ++d) { float p = P[(t << 6) + d]; s = fmaf(p, p, s); }
      A[t] = s;
    } else if (t < 128) {
      int hw = t - 64; float s = 0.f;
      for (int d = 0; d < 64; ++d) { float q = Q[(hw << 6) + d]; s = fmaf(q, q, s); }
      Cc[hw] = s;
    } else if (t < 160) {
      int f = t - 128; float s = 0.f;
      for (int e = 0; e < 64; ++e) s += w1[(f << 6) + e];
      s1[f] = s;
    }
    for (int i = t; i < 2048; i += 256) {
      int f = i >> 6, d = i & 63;
      float s = 0.f;
      for (int e = 0; e < 64; ++e) s = fmaf(w1[(f << 6) + e], P[(e << 6) + d], s);
      W1P[i] = s;
    }
    __syncthreads();
    if (t < 32) {
      float s = 0.f;
      for (int e = 0; e < 64; ++e) s = fmaf(A[e], w1[(t << 6) + e], s);
      ws[WS_A1 + t] = s;
    }
    for (int i = t; i < 2048; i += 256) {
      int f = i >> 6, hw = i & 63;
      float s = 0.f;
      for (int d = 0; d < 64; ++d) s = fmaf(W1P[(f << 6) + d], Q[(hw << 6) + d], s);
      ws[WS_BT + i] = s;
      ws[WS_CT + i] = fmaf(Cc[hw], s1[f], b1[f]);
    }
  }
}

// ---------------- K3: conv2 + rel ----------------
__global__ __launch_bounds__(256) void k3_conv2_rel(
    const float* __restrict__ x,
    const float* __restrict__ ws,   // y1 @ WS_Y1, bt/ct/a1
    const float* __restrict__ w2, const float* __restrict__ b2,
    const float* __restrict__ c2w, const float* __restrict__ c2b,
    float* __restrict__ out) {
  __shared__ float lds[12800];
  int bid = blockIdx.x, t = threadIdx.x;

  if (bid < 128) {
    // ---- conv2 role: 3x3 SAME, 128->128 ch
    float* yp = lds;                 // [128][10][10] zero-padded
    int b = bid >> 5, chunk = bid & 31;
    const float* y1 = ws + WS_Y1;
    for (int i = t; i < 12800; i += 256) yp[i] = 0.f;
    __syncthreads();
    for (int i = t; i < 8192; i += 256) {
      int ci = i >> 6, hw = i & 63;
      yp[ci * 100 + ((hw >> 3) + 1) * 10 + (hw & 7) + 1] = y1[(((b << 7) + ci) << 6) + hw];
    }
    __syncthreads();
    int hw = t & 63, wv = t >> 6;
    int h = hw >> 3, ww = hw & 7;
    int co = (chunk << 2) + wv;
    float acc = c2b[co];
    const float* wc = c2w + co * 1152;
    for (int ci = 0; ci < 128; ++ci) {
      const float* xr = yp + ci * 100 + h * 10 + ww;
      const float* wr = wc + ci * 9;
#pragma unroll
      for (int dy = 0; dy < 3; ++dy)
#pragma unroll
        for (int dx = 0; dx < 3; ++dx)
          acc = fmaf(xr[dy * 10 + dx], wr[dy * 3 + dx], acc);
    }
    out[ANT_OFF + (((b << 7) + co) << 6) + hw] = acc;
  } else {
    // ---- rel role: closed-form rel_out, block per (b,c)
    float* xl  = lds;          // [s][hw] 4096
    float* a1l = lds + 4096;   // 32
    float* w2l = lds + 4128;   // 32
    float* red = lds + 4160;   // 8
    int bc = bid - 128; int b = bc >> 6, c = bc & 63;
    for (int i = t; i < 4096; i += 256) {
      int s = i >> 6, hw = i & 63;
      xl[i] = x[((b * 65 + s) << 6) + hw];
    }
    if (t < 32) { a1l[t] = ws[WS_A1 + t]; w2l[t] = w2[t]; }
    if (t < 8) red[t] = 0.f;
    int hw = t & 63, sg = t >> 6;
    float btr[32], ctr[32];
#pragma unroll
    for (int f = 0; f < 32; ++f) {
      btr[f] = ws[WS_BT + (f << 6) + hw];
      ctr[f] = ws[WS_CT + (f << 6) + hw];
    }
    __syncthreads();
    float b2v = b2[0];
    float xc = xl[(c << 6) + hw];
    float partial = 0.f;
    for (int s = sg; s < 64; s += 4) {
      float xs = xl[(s << 6) + hw];
      float u = xc * xs, v = xc + xs;
      float acc = b2v;
#pragma unroll
      for (int f = 0; f < 32; ++f) {
        float tt = fmaf(u, a1l[f], fmaf(v, btr[f], ctr[f]));
        acc = fmaf(fmaxf(tt, 0.f), w2l[f], acc);
      }
      partial += acc;
    }
    atomicAdd(&red[hw & 7], partial);
    __syncthreads();
    if (t < 8) out[REL_OFF + bc * 8 + t] = red[t];
  }
}

extern "C" void kernel_launch(void* const* d_in, const int* in_sizes, int n_in,
                              void* d_out, int out_size, void* d_ws, size_t ws_size,
                              hipStream_t stream) {
  const float* x     = (const float*)d_in[0];
  const float* piece = (const float*)d_in[1];
  const float* pos   = (const float*)d_in[2];
  const float* w1    = (const float*)d_in[3];
  const float* b1    = (const float*)d_in[4];
  const float* w2    = (const float*)d_in[5];
  const float* b2    = (const float*)d_in[6];
  const float* c1w   = (const float*)d_in[7];
  const float* c1b   = (const float*)d_in[8];
  const float* c2w   = (const float*)d_in[9];
  const float* c2b   = (const float*)d_in[10];
  float* out = (float*)d_out;
  float* ws  = (float*)d_ws;

  k2_se_conv1_pre<<<SE_BASE + SE_BLOCKS, 256, 0, stream>>>(
      x, piece, pos, w1, b1, c1w, c1b, out, ws);
  k3_conv2_rel<<<384, 256, 0, stream>>>(x, ws, w2, b2, c2w, c2b, out);
}